// Round 1
// baseline (3165.609 us; speedup 1.0000x reference)
//
#include <hip/hip_runtime.h>

using u16 = unsigned short;
using u32 = unsigned int;

typedef __bf16 bf16x8 __attribute__((ext_vector_type(8)));
typedef float f32x4 __attribute__((ext_vector_type(4)));

#define MREAL 39200   // 200 windows * 196 tokens
#define MPAD  39296   // padded to 307*128

__device__ __forceinline__ u16 f2bf(float f) {
  u32 u = __float_as_uint(f);
  u += 0x7fffu + ((u >> 16) & 1u);   // RNE
  return (u16)(u >> 16);
}
__device__ __forceinline__ float bflo(u32 w) { return __uint_as_float(w << 16); }
__device__ __forceinline__ float bfhi(u32 w) { return __uint_as_float(w & 0xffff0000u); }

__device__ __forceinline__ void async16(const void* g, void* l) {
  __builtin_amdgcn_global_load_lds((const __attribute__((address_space(1))) void*)g,
                                   (__attribute__((address_space(3))) void*)l, 16, 0, 0);
}

// ---------------- prep: weights fp32 -> bf16 ----------------
__global__ __launch_bounds__(256) void prep_w(const float* __restrict__ qw,
                                              const float* __restrict__ pw,
                                              u16* __restrict__ qwb, u16* __restrict__ pwb) {
  int i = blockIdx.x * 256 + threadIdx.x;
  if (i < 2304 * 768) qwb[i] = f2bf(qw[i]);
  if (i < 768 * 768)  pwb[i] = f2bf(pw[i]);
}

// ---------------- window partition: x(8,64,64,768) fp32 -> Xw(MPAD,768) bf16 ----------------
__global__ __launch_bounds__(256) void build_xw(const float* __restrict__ x, u16* __restrict__ Xw) {
  int bid = blockIdx.x;
  int m = bid / 3;
  int c = (bid % 3) * 256 + threadIdx.x;
  float val = 0.f;
  if (m < MREAL) {
    int w = m / 196, t = m % 196;
    int b = w / 25, r = w % 25;
    int gh = (r / 5) * 14 + t / 14;   // 5x5 windows of 14, pad 70
    int gw = (r % 5) * 14 + t % 14;
    if (gh < 64 && gw < 64)
      val = x[(((size_t)b * 64 + gh) * 64 + gw) * 768 + c];
  }
  Xw[(size_t)m * 768 + c] = f2bf(val);
}

// ---------------- NT GEMM: C[m][n] = sum_k A[m][k]*B[n][k] + bias[n] ----------------
// 128x128 tile, BK=32, 4 waves in 2x2, each wave 4x4 frags of 16x16x32 bf16 MFMA.
// EPI=0: store bf16 row-major.  EPI=1: fp32 scatter with window-unpartition + crop.
template<int EPI>
__global__ __launch_bounds__(256) void gemm_bt(
    const u16* __restrict__ A, const u16* __restrict__ B,
    const float* __restrict__ bias, u16* __restrict__ Cb,
    float* __restrict__ Cf, int K, int N)
{
  __shared__ u16 As[128 * 32];
  __shared__ u16 Bs[128 * 32];
  const int tid = threadIdx.x;
  const int m0 = blockIdx.y * 128;
  const int n0 = blockIdx.x * 128;
  const int lane = tid & 63;
  const int wv = tid >> 6;
  const int wm = wv >> 1, wn = wv & 1;
  const int lr = lane & 15, lq = lane >> 4;

  f32x4 acc[4][4];
#pragma unroll
  for (int i = 0; i < 4; i++)
#pragma unroll
    for (int j = 0; j < 4; j++)
      acc[i][j] = f32x4{0.f, 0.f, 0.f, 0.f};

  const int rr_ = tid >> 2, cq = tid & 3;                  // chunk: row, 8-elem k-chunk
  const u16* A0 = A + (size_t)(m0 + rr_) * K + cq * 8;
  const u16* A1 = A0 + (size_t)64 * K;
  const u16* B0 = B + (size_t)(n0 + rr_) * K + cq * 8;
  const u16* B1 = B0 + (size_t)64 * K;

  for (int k0 = 0; k0 < K; k0 += 32) {
    __syncthreads();                    // LDS free (prev iter reads done)
    async16(A0 + k0, (void*)(As + tid * 8));
    async16(A1 + k0, (void*)(As + 2048 + tid * 8));
    async16(B0 + k0, (void*)(Bs + tid * 8));
    async16(B1 + k0, (void*)(Bs + 2048 + tid * 8));
    __syncthreads();                    // copies landed (compiler drains vmcnt)

    union { uint4 u; bf16x8 b; } af[4], bg[4];
#pragma unroll
    for (int i = 0; i < 4; i++) {
      af[i].u = *(const uint4*)(As + (wm * 64 + i * 16 + lr) * 32 + lq * 8);
      bg[i].u = *(const uint4*)(Bs + (wn * 64 + i * 16 + lr) * 32 + lq * 8);
    }
#pragma unroll
    for (int i = 0; i < 4; i++)
#pragma unroll
      for (int j = 0; j < 4; j++)
        acc[i][j] = __builtin_amdgcn_mfma_f32_16x16x32_bf16(af[i].b, bg[j].b, acc[i][j], 0, 0, 0);
  }

#pragma unroll
  for (int i = 0; i < 4; i++) {
#pragma unroll
    for (int j = 0; j < 4; j++) {
      const int n = n0 + wn * 64 + j * 16 + lr;
      const int mb = m0 + wm * 64 + i * 16 + lq * 4;
      const float bv = bias[n];
#pragma unroll
      for (int rr = 0; rr < 4; rr++) {
        float val = acc[i][j][rr] + bv;
        int m = mb + rr;
        if (EPI == 0) {
          Cb[(size_t)m * N + n] = f2bf(val);
        } else {
          if (m < MREAL) {
            int wdx = m / 196, tt = m % 196;
            int b = wdx / 25, rwd = wdx % 25;
            int gh = (rwd / 5) * 14 + tt / 14;
            int gw = (rwd % 5) * 14 + tt % 14;
            if (gh < 64 && gw < 64)
              Cf[(((size_t)b * 64 + gh) * 64 + gw) * 768 + n] = val;
          }
        }
      }
    }
  }
}

// ---------------- fused attention: one block per (window, head) ----------------
// qkv bf16 [m][s*768 + h*64 + d]; RoPE applied on the fly to q,k; rel-pos via dots
// against LDS tables; flash-style online softmax over 7 tiles of 28 keys.
__global__ __launch_bounds__(256, 2) void attn_fused(
    const u16* __restrict__ qkv, u16* __restrict__ ao,
    const float* __restrict__ relph, const float* __restrict__ relpw)
{
  const int blk = blockIdx.x;
  const int w = blk / 12, h = blk % 12;
  const int tid = threadIdx.x;

  __shared__ u16 kls[28 * 64];     // roped k tile, bf16
  __shared__ u16 vls[28 * 64];     // v tile, bf16
  __shared__ float rhs[27 * 64];   // rel_pos_h table
  __shared__ float rws[27 * 64];   // rel_pos_w table

  for (int i = tid; i < 27 * 64; i += 256) { rhs[i] = relph[i]; rws[i] = relpw[i]; }

  const int t = tid;
  const bool act = (t < 196);
  float qreg[64];
  float relw[14];
  float acc[64];
#pragma unroll
  for (int d = 0; d < 64; d++) acc[d] = 0.f;
  float mrun = -3e38f, lrun = 0.f;
  int qy = 0, qx = 0;

  if (act) {
    const u16* qp = qkv + (size_t)(w * 196 + t) * 2304 + h * 64;
#pragma unroll
    for (int u = 0; u < 8; u++) {
      uint4 q4 = *(const uint4*)(qp + u * 8);
      qreg[u*8+0] = bflo(q4.x); qreg[u*8+1] = bfhi(q4.x);
      qreg[u*8+2] = bflo(q4.y); qreg[u*8+3] = bfhi(q4.y);
      qreg[u*8+4] = bflo(q4.z); qreg[u*8+5] = bfhi(q4.z);
      qreg[u*8+6] = bflo(q4.w); qreg[u*8+7] = bfhi(q4.w);
    }
    qy = t / 14; qx = t % 14;
    const float tx = (float)qx, ty = (float)qy;
#pragma unroll
    for (int f = 0; f < 32; f++) {                 // axial rope: f<16 uses x, else y
      float fr = __powf(10000.f, -(float)(f & 15) * (1.f / 16.f));
      float ang = (f < 16 ? tx : ty) * fr;
      float c, s; __sincosf(ang, &s, &c);
      float xr = qreg[2*f], xi = qreg[2*f+1];
      qreg[2*f]   = xr * c - xi * s;
      qreg[2*f+1] = xr * s + xi * c;
    }
  }
  __syncthreads();   // rel tables ready
  if (act) {
#pragma unroll
    for (int kk = 0; kk < 14; kk++) {              // rel_w[kj] = q . rel_pos_w[qx-kj+13]
      const float* rp = &rws[(qx - kk + 13) * 64];
      float s = 0.f;
#pragma unroll
      for (int d = 0; d < 64; d++) s += qreg[d] * rp[d];
      relw[kk] = s;
    }
  }

  for (int nt = 0; nt < 7; nt++) {
    __syncthreads();
    if (tid < 224) {                               // stage 28 k,v rows; rope k
      const int jj = tid >> 3, cc = (tid & 7) * 8;
      const int tk = nt * 28 + jj;
      const u16* kp = qkv + (size_t)(w * 196 + tk) * 2304 + 768 + h * 64 + cc;
      uint4 v4 = *(const uint4*)(kp + 768);
      *(uint4*)(vls + jj * 64 + cc) = v4;
      uint4 k4 = *(const uint4*)kp;
      float kf[8];
      kf[0]=bflo(k4.x); kf[1]=bfhi(k4.x); kf[2]=bflo(k4.y); kf[3]=bfhi(k4.y);
      kf[4]=bflo(k4.z); kf[5]=bfhi(k4.z); kf[6]=bflo(k4.w); kf[7]=bfhi(k4.w);
      const float tx = (float)(tk % 14), ty = (float)(tk / 14);
#pragma unroll
      for (int p = 0; p < 4; p++) {
        int f = (cc >> 1) + p;
        float fr = __powf(10000.f, -(float)(f & 15) * (1.f / 16.f));
        float ang = (f < 16 ? tx : ty) * fr;
        float c, s; __sincosf(ang, &s, &c);
        float xr = kf[2*p], xi = kf[2*p+1];
        kf[2*p]   = xr * c - xi * s;
        kf[2*p+1] = xr * s + xi * c;
      }
      u32 p0 = (u32)f2bf(kf[0]) | ((u32)f2bf(kf[1]) << 16);
      u32 p1 = (u32)f2bf(kf[2]) | ((u32)f2bf(kf[3]) << 16);
      u32 p2 = (u32)f2bf(kf[4]) | ((u32)f2bf(kf[5]) << 16);
      u32 p3 = (u32)f2bf(kf[6]) | ((u32)f2bf(kf[7]) << 16);
      *(uint4*)(kls + jj * 64 + cc) = make_uint4(p0, p1, p2, p3);
    }
    __syncthreads();
    if (act) {
#pragma unroll
      for (int half = 0; half < 2; half++) {       // 14 keys share one rel_h value
        const int ky = nt * 2 + half;
        const float* rp = &rhs[(qy - ky + 13) * 64];
        float rhv = 0.f;
#pragma unroll
        for (int d = 0; d < 64; d++) rhv += qreg[d] * rp[d];
        float sreg[14];
        float tmax = mrun;
#pragma unroll
        for (int j = 0; j < 14; j++) {
          const u16* krow = kls + (half * 14 + j) * 64;
          float dot = 0.f;
#pragma unroll
          for (int u = 0; u < 8; u++) {
            uint4 kk4 = *(const uint4*)(krow + u * 8);
            dot += qreg[u*8+0]*bflo(kk4.x) + qreg[u*8+1]*bfhi(kk4.x);
            dot += qreg[u*8+2]*bflo(kk4.y) + qreg[u*8+3]*bfhi(kk4.y);
            dot += qreg[u*8+4]*bflo(kk4.z) + qreg[u*8+5]*bfhi(kk4.z);
            dot += qreg[u*8+6]*bflo(kk4.w) + qreg[u*8+7]*bfhi(kk4.w);
          }
          float sc = dot * 0.125f + rhv + relw[j];
          sreg[j] = sc;
          tmax = fmaxf(tmax, sc);
        }
        float alpha = __expf(mrun - tmax);
        mrun = tmax;
        lrun *= alpha;
#pragma unroll
        for (int d = 0; d < 64; d++) acc[d] *= alpha;
#pragma unroll
        for (int j = 0; j < 14; j++) {
          float p = __expf(sreg[j] - tmax);
          lrun += p;
          const u16* vrow = vls + (half * 14 + j) * 64;
#pragma unroll
          for (int u = 0; u < 8; u++) {
            uint4 vv4 = *(const uint4*)(vrow + u * 8);
            acc[u*8+0] += p * bflo(vv4.x); acc[u*8+1] += p * bfhi(vv4.x);
            acc[u*8+2] += p * bflo(vv4.y); acc[u*8+3] += p * bfhi(vv4.y);
            acc[u*8+4] += p * bflo(vv4.z); acc[u*8+5] += p * bfhi(vv4.z);
            acc[u*8+6] += p * bflo(vv4.w); acc[u*8+7] += p * bfhi(vv4.w);
          }
        }
      }
    }
  }
  if (act) {
    float inv = 1.f / lrun;
    u16* op = ao + (size_t)(w * 196 + t) * 768 + h * 64;   // [w][t][h][d] = [m][C]
#pragma unroll
    for (int u = 0; u < 8; u++) {
      u32 p0 = (u32)f2bf(acc[u*8+0]*inv) | ((u32)f2bf(acc[u*8+1]*inv) << 16);
      u32 p1 = (u32)f2bf(acc[u*8+2]*inv) | ((u32)f2bf(acc[u*8+3]*inv) << 16);
      u32 p2 = (u32)f2bf(acc[u*8+4]*inv) | ((u32)f2bf(acc[u*8+5]*inv) << 16);
      u32 p3 = (u32)f2bf(acc[u*8+6]*inv) | ((u32)f2bf(acc[u*8+7]*inv) << 16);
      *(uint4*)(op + u * 8) = make_uint4(p0, p1, p2, p3);
    }
  }
}

extern "C" void kernel_launch(void* const* d_in, const int* in_sizes, int n_in,
                              void* d_out, int out_size, void* d_ws, size_t ws_size,
                              hipStream_t stream) {
  const float* x      = (const float*)d_in[0];
  const float* qkv_w  = (const float*)d_in[1];
  const float* qkv_b  = (const float*)d_in[2];
  const float* proj_w = (const float*)d_in[3];
  const float* proj_b = (const float*)d_in[4];
  const float* rel_h  = (const float*)d_in[5];
  const float* rel_w  = (const float*)d_in[6];
  float* out = (float*)d_out;

  // ws layout (bytes): Xw/attn_out 60,358,656 | qkv 181,075,968 | qkv_w bf16 3,538,944 | proj_w bf16 1,179,648
  char* ws = (char*)d_ws;
  u16* Xw   = (u16*)ws;                                                   // MPAD*768, aliased as attn_out later
  u16* qkvb = (u16*)(ws + (size_t)MPAD * 768 * 2);                        // MPAD*2304
  u16* qwb  = (u16*)(ws + (size_t)MPAD * 768 * 2 + (size_t)MPAD * 2304 * 2);
  u16* pwb  = (u16*)((char*)qwb + (size_t)2304 * 768 * 2);

  prep_w<<<6912, 256, 0, stream>>>(qkv_w, proj_w, qwb, pwb);
  build_xw<<<MPAD * 3, 256, 0, stream>>>(x, Xw);
  // qkv = Xw @ qkv_w^T + qkv_b   (M=39296 padded, N=2304, K=768)
  gemm_bt<0><<<dim3(18, 307), 256, 0, stream>>>(Xw, qwb, qkv_b, qkvb, nullptr, 768, 2304);
  // fused rope + rel-pos attention; writes attn_out into Xw region ([m][C], bf16)
  attn_fused<<<2400, 256, 0, stream>>>(qkvb, Xw, rel_h, rel_w);
  // out = attn_out @ proj_w^T + proj_b, scattered to (B,64,64,768) fp32 with crop
  gemm_bt<1><<<dim3(6, 307), 256, 0, stream>>>(Xw, pwb, proj_b, nullptr, out, 768, 768);
}

// Round 3
// 791.317 us; speedup vs baseline: 4.0004x; 4.0004x over previous
//
#include <hip/hip_runtime.h>

using u16 = unsigned short;
using u32 = unsigned int;

typedef __bf16 bf16x8 __attribute__((ext_vector_type(8)));
typedef float f32x4 __attribute__((ext_vector_type(4)));

#define MREAL 39200   // 200 windows * 196 tokens
#define MPAD  39296   // padded to 307*128

__device__ __forceinline__ u16 f2bf(float f) {
  u32 u = __float_as_uint(f);
  u += 0x7fffu + ((u >> 16) & 1u);   // RNE
  return (u16)(u >> 16);
}
__device__ __forceinline__ u32 pkbf(float a, float b) {
  return (u32)f2bf(a) | ((u32)f2bf(b) << 16);
}
__device__ __forceinline__ float bflo(u32 w) { return __uint_as_float(w << 16); }
__device__ __forceinline__ float bfhi(u32 w) { return __uint_as_float(w & 0xffff0000u); }

__device__ __forceinline__ void async16(const void* g, void* l) {
  __builtin_amdgcn_global_load_lds((const __attribute__((address_space(1))) void*)g,
                                   (__attribute__((address_space(3))) void*)l, 16, 0, 0);
}

union frag { uint4 u; bf16x8 b; };

// ---------------- prep: weights fp32 -> bf16, rope cos/sin table ----------------
__global__ __launch_bounds__(256) void prep_w(const float* __restrict__ qw,
                                              const float* __restrict__ pw,
                                              u16* __restrict__ qwb, u16* __restrict__ pwb,
                                              float2* __restrict__ cs) {
  int i = blockIdx.x * 256 + threadIdx.x;
  if (i < 2304 * 768) qwb[i] = f2bf(qw[i]);
  if (i < 768 * 768)  pwb[i] = f2bf(pw[i]);
  if (i < 196 * 32) {
    int t = i >> 5, f = i & 31;
    float fr = powf(10000.f, -(float)(f & 15) * (1.f / 16.f));
    float ang = (f < 16 ? (float)(t % 14) : (float)(t / 14)) * fr;
    cs[i] = make_float2(cosf(ang), sinf(ang));
  }
}

// ---------------- window partition: x(8,64,64,768) fp32 -> Xw(MPAD,768) bf16 ----------------
__global__ __launch_bounds__(256) void build_xw(const float* __restrict__ x, u16* __restrict__ Xw) {
  int bid = blockIdx.x;
  int m = bid / 3;
  int c = (bid % 3) * 256 + threadIdx.x;
  float val = 0.f;
  if (m < MREAL) {
    int w = m / 196, t = m % 196;
    int b = w / 25, r = w % 25;
    int gh = (r / 5) * 14 + t / 14;
    int gw = (r % 5) * 14 + t % 14;
    if (gh < 64 && gw < 64)
      val = x[(((size_t)b * 64 + gh) * 64 + gw) * 768 + c];
  }
  Xw[(size_t)m * 768 + c] = f2bf(val);
}

// ---------------- NT GEMM (m97-style) ----------------
template<int EPI>
__global__ __launch_bounds__(256) void gemm_bt(
    const u16* __restrict__ A, const u16* __restrict__ B,
    const float* __restrict__ bias, u16* __restrict__ Cb,
    float* __restrict__ Cf, int K, int N)
{
  __shared__ u16 As[128 * 32];
  __shared__ u16 Bs[128 * 32];
  const int tid = threadIdx.x;
  const int m0 = blockIdx.y * 128;
  const int n0 = blockIdx.x * 128;
  const int lane = tid & 63;
  const int wv = tid >> 6;
  const int wm = wv >> 1, wn = wv & 1;
  const int lr = lane & 15, lq = lane >> 4;

  f32x4 acc[4][4];
#pragma unroll
  for (int i = 0; i < 4; i++)
#pragma unroll
    for (int j = 0; j < 4; j++)
      acc[i][j] = f32x4{0.f, 0.f, 0.f, 0.f};

  const int rr_ = tid >> 2, cq = tid & 3;
  const u16* A0 = A + (size_t)(m0 + rr_) * K + cq * 8;
  const u16* A1 = A0 + (size_t)64 * K;
  const u16* B0 = B + (size_t)(n0 + rr_) * K + cq * 8;
  const u16* B1 = B0 + (size_t)64 * K;

  for (int k0 = 0; k0 < K; k0 += 32) {
    __syncthreads();
    async16(A0 + k0, (void*)(As + tid * 8));
    async16(A1 + k0, (void*)(As + 2048 + tid * 8));
    async16(B0 + k0, (void*)(Bs + tid * 8));
    async16(B1 + k0, (void*)(Bs + 2048 + tid * 8));
    __syncthreads();

    frag af[4], bg[4];
#pragma unroll
    for (int i = 0; i < 4; i++) {
      af[i].u = *(const uint4*)(As + (wm * 64 + i * 16 + lr) * 32 + lq * 8);
      bg[i].u = *(const uint4*)(Bs + (wn * 64 + i * 16 + lr) * 32 + lq * 8);
    }
#pragma unroll
    for (int i = 0; i < 4; i++)
#pragma unroll
      for (int j = 0; j < 4; j++)
        acc[i][j] = __builtin_amdgcn_mfma_f32_16x16x32_bf16(af[i].b, bg[j].b, acc[i][j], 0, 0, 0);
  }

#pragma unroll
  for (int i = 0; i < 4; i++) {
#pragma unroll
    for (int j = 0; j < 4; j++) {
      const int n = n0 + wn * 64 + j * 16 + lr;
      const int mb = m0 + wm * 64 + i * 16 + lq * 4;
      const float bv = bias[n];
#pragma unroll
      for (int rr = 0; rr < 4; rr++) {
        float val = acc[i][j][rr] + bv;
        int m = mb + rr;
        if (EPI == 0) {
          if (m < MREAL) Cb[(size_t)m * N + n] = f2bf(val);
        } else {
          if (m < MREAL) {
            int wdx = m / 196, tt = m % 196;
            int b = wdx / 25, rwd = wdx % 25;
            int gh = (rwd / 5) * 14 + tt / 14;
            int gw = (rwd % 5) * 14 + tt % 14;
            if (gh < 64 && gw < 64)
              Cf[(((size_t)b * 64 + gh) * 64 + gw) * 768 + n] = val;
          }
        }
      }
    }
  }
}

// ---------------- MFMA attention ----------------
// One block per (window, head). 4 waves x 64 query rows (196 real, pad 256).
// Keys padded to 224. Aug K-dim = 96: [q/8 | RH 14 | RW 14 | -30 flag | 0 0 0].
// P = exp(s) (no max-subtract; scores are O(1) by construction), l via MFMA vs ones.
#define R1P 104   // K_aug / A_aug row pitch (bf16 elems)
#define VTP 232   // V^T row pitch
#define PBP 40    // P buffer row pitch
#define LDS_R1   (256 * R1P * 2)                 // 53248
#define LDS_VT   (64 * VTP * 2)                  // 29696  (aliases Th/Tw 28672)
#define LDS_PB   (4 * 64 * PBP * 2)              // 20480  (aliases RT 17408)
#define LDS_TOT  (LDS_R1 + LDS_VT + LDS_PB)      // 103424

__global__ __launch_bounds__(256, 1) void attn_mfma(
    const u16* __restrict__ qkv, u16* __restrict__ ao,
    const float* __restrict__ relph, const float* __restrict__ relpw,
    const float2* __restrict__ cs)
{
  extern __shared__ char smem[];
  u16*   R1  = (u16*)smem;                       // [256][R1P]
  u16*   VTb = (u16*)(smem + LDS_R1);            // V^T [64][VTP]
  u16*   Th  = VTb;                              // phase-A alias: [256][28]
  u16*   Tw  = VTb + 256 * 28;
  char*  PBr = smem + LDS_R1 + LDS_VT;
  float* RTh = (float*)PBr;                      // phase-A alias: [32][68]
  float* RTw = RTh + 32 * 68;

  const int blk = blockIdx.x;
  const int w = blk / 12, h = blk % 12;
  const int tid = threadIdx.x;
  const int lane = tid & 63, wv = tid >> 6;
  const int lr = lane & 15, lq = lane >> 4;

  // ---- phase 0: rel tables -> RT (rows 27..31 zero) ----
  for (int i = tid; i < 32 * 64; i += 256) {
    int r = i >> 6, d = i & 63;
    float vh = 0.f, vw = 0.f;
    if (r < 27) { vh = relph[r * 64 + d]; vw = relpw[r * 64 + d]; }
    RTh[r * 68 + d] = vh;
    RTw[r * 68 + d] = vw;
  }

  // ---- phase A1: roped, scaled q -> R1 cols 0..63 ----
  {
    float qf[64];
    if (tid < 196) {
      const u16* qp = qkv + (size_t)(w * 196 + tid) * 2304 + h * 64;
      uint4 q4[8];
#pragma unroll
      for (int u = 0; u < 8; u++) q4[u] = *(const uint4*)(qp + u * 8);
#pragma unroll
      for (int u = 0; u < 8; u++) {
        qf[u*8+0] = bflo(q4[u].x); qf[u*8+1] = bfhi(q4[u].x);
        qf[u*8+2] = bflo(q4[u].y); qf[u*8+3] = bfhi(q4[u].y);
        qf[u*8+4] = bflo(q4[u].z); qf[u*8+5] = bfhi(q4[u].z);
        qf[u*8+6] = bflo(q4[u].w); qf[u*8+7] = bfhi(q4[u].w);
      }
      const float2* ct = cs + tid * 32;
#pragma unroll
      for (int f = 0; f < 32; f++) {
        float2 c2 = ct[f];
        float xr = qf[2*f], xi = qf[2*f+1];
        qf[2*f]   = (xr * c2.x - xi * c2.y) * 0.125f;
        qf[2*f+1] = (xr * c2.y + xi * c2.x) * 0.125f;
      }
    } else {
#pragma unroll
      for (int d = 0; d < 64; d++) qf[d] = 0.f;
    }
    u16* dst = R1 + tid * R1P;
#pragma unroll
    for (int u = 0; u < 8; u++)
      *(uint4*)(dst + u * 8) = make_uint4(pkbf(qf[u*8+0], qf[u*8+1]), pkbf(qf[u*8+2], qf[u*8+3]),
                                          pkbf(qf[u*8+4], qf[u*8+5]), pkbf(qf[u*8+6], qf[u*8+7]));
  }
  __syncthreads();

  // ---- phase A2: A-frags (q part) + T tables via MFMA ----
  frag af[4][3];
#pragma unroll
  for (int i = 0; i < 4; i++)
#pragma unroll
    for (int kc = 0; kc < 2; kc++)
      af[i][kc].u = *(const uint4*)(R1 + (wv * 64 + i * 16 + lr) * R1P + kc * 32 + lq * 8);

#pragma unroll
  for (int n = 0; n < 2; n++) {
    f32x4 tah[4], taw[4];
#pragma unroll
    for (int i = 0; i < 4; i++) { tah[i] = f32x4{0,0,0,0}; taw[i] = f32x4{0,0,0,0}; }
#pragma unroll
    for (int kc = 0; kc < 2; kc++) {
      const float* ph = &RTh[(n * 16 + lr) * 68 + kc * 32 + lq * 8];
      const float* pw2 = &RTw[(n * 16 + lr) * 68 + kc * 32 + lq * 8];
      float4 ha = *(const float4*)ph, hb = *(const float4*)(ph + 4);
      float4 wa = *(const float4*)pw2, wb2 = *(const float4*)(pw2 + 4);
      frag bh, bw;
      bh.u = make_uint4(pkbf(ha.x, ha.y), pkbf(ha.z, ha.w), pkbf(hb.x, hb.y), pkbf(hb.z, hb.w));
      bw.u = make_uint4(pkbf(wa.x, wa.y), pkbf(wa.z, wa.w), pkbf(wb2.x, wb2.y), pkbf(wb2.z, wb2.w));
#pragma unroll
      for (int i = 0; i < 4; i++) {
        tah[i] = __builtin_amdgcn_mfma_f32_16x16x32_bf16(af[i][kc].b, bh.b, tah[i], 0, 0, 0);
        taw[i] = __builtin_amdgcn_mfma_f32_16x16x32_bf16(af[i][kc].b, bw.b, taw[i], 0, 0, 0);
      }
    }
    int jcol = n * 16 + lr;
    if (jcol < 28) {
#pragma unroll
      for (int i = 0; i < 4; i++)
#pragma unroll
        for (int r = 0; r < 4; r++) {
          int q = wv * 64 + i * 16 + lq * 4 + r;
          Th[q * 28 + jcol] = f2bf(tah[i][r] * 8.f);   // undo q*0.125
          Tw[q * 28 + jcol] = f2bf(taw[i][r] * 8.f);
        }
    }
  }
  __syncthreads();

  // ---- phase A3: gather RH/RW -> R1 cols 64..95 ----
  {
    u32 wb[16];
#pragma unroll
    for (int z = 0; z < 16; z++) wb[z] = 0;
    if (tid < 196) {
      int ty = tid / 14, tx = tid - ty * 14;
      const u16* thr = Th + tid * 28 + ty + 13;
      const u16* twr = Tw + tid * 28 + tx + 13;
#pragma unroll
      for (int p = 0; p < 7; p++) wb[p]     = (u32)thr[-(2*p)] | ((u32)thr[-(2*p+1)] << 16);
#pragma unroll
      for (int p = 0; p < 7; p++) wb[7 + p] = (u32)twr[-(2*p)] | ((u32)twr[-(2*p+1)] << 16);
    }
    wb[14] = 0xC1F0u;   // col 92 = bf16(-30); col 93 = 0
    u16* dst = R1 + tid * R1P + 64;
#pragma unroll
    for (int u = 0; u < 4; u++)
      *(uint4*)(dst + u * 8) = make_uint4(wb[u*4], wb[u*4+1], wb[u*4+2], wb[u*4+3]);
  }
  __syncthreads();

  // ---- phase A4: A-frag bias chunk ----
#pragma unroll
  for (int i = 0; i < 4; i++)
    af[i][2].u = *(const uint4*)(R1 + (wv * 64 + i * 16 + lr) * R1P + 64 + lq * 8);
  __syncthreads();

  // ---- phase B: K_aug -> R1 rows 0..223, V^T -> VTb ----
  if (tid < 224) {
    u32 kw[48];
#pragma unroll
    for (int z = 0; z < 48; z++) kw[z] = 0;
    if (tid < 196) {
      const u16* kp = qkv + (size_t)(w * 196 + tid) * 2304 + 768 + h * 64;
      float kf[64];
      uint4 k4[8];
#pragma unroll
      for (int u = 0; u < 8; u++) k4[u] = *(const uint4*)(kp + u * 8);
#pragma unroll
      for (int u = 0; u < 8; u++) {
        kf[u*8+0] = bflo(k4[u].x); kf[u*8+1] = bfhi(k4[u].x);
        kf[u*8+2] = bflo(k4[u].y); kf[u*8+3] = bfhi(k4[u].y);
        kf[u*8+4] = bflo(k4[u].z); kf[u*8+5] = bfhi(k4[u].z);
        kf[u*8+6] = bflo(k4[u].w); kf[u*8+7] = bfhi(k4[u].w);
      }
      const float2* ct = cs + tid * 32;
#pragma unroll
      for (int f = 0; f < 32; f++) {
        float2 c2 = ct[f];
        float xr = kf[2*f], xi = kf[2*f+1];
        kf[2*f]   = xr * c2.x - xi * c2.y;
        kf[2*f+1] = xr * c2.y + xi * c2.x;
      }
#pragma unroll
      for (int p = 0; p < 32; p++) kw[p] = pkbf(kf[2*p], kf[2*p+1]);
      int ky = tid / 14, kx = tid - ky * 14;
      int ch = 64 + ky;  kw[ch >> 1] |= 0x3F80u << ((ch & 1) * 16);
      int cw = 78 + kx;  kw[cw >> 1] |= 0x3F80u << ((cw & 1) * 16);
    } else {
      kw[46] = 0x3F80u;  // pad-key flag col 92 = 1.0
    }
    u16* dst = R1 + tid * R1P;
#pragma unroll
    for (int u = 0; u < 12; u++)   // FIX: 12x16B = all 96 aug columns (was 6 -> stale -30 col read back => exp overflow => NaN)
      *(uint4*)(dst + u * 8) = make_uint4(kw[u*4], kw[u*4+1], kw[u*4+2], kw[u*4+3]);

    // V^T (keep raw bf16 bits)
    if (tid < 196) {
      const u16* vp = qkv + (size_t)(w * 196 + tid) * 2304 + 1536 + h * 64;
#pragma unroll
      for (int u = 0; u < 8; u++) {
        uint4 v4 = *(const uint4*)(vp + u * 8);
        u16* col = VTb + tid;
        col[(u*8+0) * VTP] = (u16)(v4.x & 0xffff); col[(u*8+1) * VTP] = (u16)(v4.x >> 16);
        col[(u*8+2) * VTP] = (u16)(v4.y & 0xffff); col[(u*8+3) * VTP] = (u16)(v4.y >> 16);
        col[(u*8+4) * VTP] = (u16)(v4.z & 0xffff); col[(u*8+5) * VTP] = (u16)(v4.z >> 16);
        col[(u*8+6) * VTP] = (u16)(v4.w & 0xffff); col[(u*8+7) * VTP] = (u16)(v4.w >> 16);
      }
    } else {
#pragma unroll
      for (int d = 0; d < 64; d++) VTb[d * VTP + tid] = 0;
    }
  }
  __syncthreads();

  // ---- main loop: 7 chunks of 32 keys, barrier-free ----
  f32x4 oacc[4][4];
  f32x4 lacc[4];
#pragma unroll
  for (int i = 0; i < 4; i++) {
    lacc[i] = f32x4{0,0,0,0};
#pragma unroll
    for (int j = 0; j < 4; j++) oacc[i][j] = f32x4{0,0,0,0};
  }
  frag ones;
  ones.u = make_uint4(0x3F803F80u, 0x3F803F80u, 0x3F803F80u, 0x3F803F80u);
  u16* PB = (u16*)PBr + wv * 64 * PBP;

  for (int c = 0; c < 7; c++) {
    frag bk[2][3];
#pragma unroll
    for (int kt = 0; kt < 2; kt++)
#pragma unroll
      for (int kc = 0; kc < 3; kc++)
        bk[kt][kc].u = *(const uint4*)(R1 + (c * 32 + kt * 16 + lr) * R1P + kc * 32 + lq * 8);

    f32x4 sacc[4][2];
#pragma unroll
    for (int i = 0; i < 4; i++) { sacc[i][0] = f32x4{0,0,0,0}; sacc[i][1] = f32x4{0,0,0,0}; }
#pragma unroll
    for (int kc = 0; kc < 3; kc++)
#pragma unroll
      for (int i = 0; i < 4; i++)
#pragma unroll
        for (int kt = 0; kt < 2; kt++)
          sacc[i][kt] = __builtin_amdgcn_mfma_f32_16x16x32_bf16(af[i][kc].b, bk[kt][kc].b, sacc[i][kt], 0, 0, 0);

    // P = exp(s) -> wave-private LDS (C-layout store, A-layout read)
#pragma unroll
    for (int i = 0; i < 4; i++)
#pragma unroll
      for (int kt = 0; kt < 2; kt++)
#pragma unroll
        for (int r = 0; r < 4; r++)
          PB[(i * 16 + lq * 4 + r) * PBP + kt * 16 + lr] = f2bf(__expf(sacc[i][kt][r]));

    frag pf[4];
#pragma unroll
    for (int i = 0; i < 4; i++)
      pf[i].u = *(const uint4*)(PB + (i * 16 + lr) * PBP + lq * 8);

#pragma unroll
    for (int i = 0; i < 4; i++)
      lacc[i] = __builtin_amdgcn_mfma_f32_16x16x32_bf16(pf[i].b, ones.b, lacc[i], 0, 0, 0);

    frag bv[4];
#pragma unroll
    for (int j = 0; j < 4; j++)
      bv[j].u = *(const uint4*)(VTb + (j * 16 + lr) * VTP + c * 32 + lq * 8);
#pragma unroll
    for (int i = 0; i < 4; i++)
#pragma unroll
      for (int j = 0; j < 4; j++)
        oacc[i][j] = __builtin_amdgcn_mfma_f32_16x16x32_bf16(pf[i].b, bv[j].b, oacc[i][j], 0, 0, 0);
  }

  // ---- epilogue: O / l -> ao [m][C] bf16 ----
#pragma unroll
  for (int i = 0; i < 4; i++) {
    f32x4 inv;
#pragma unroll
    for (int r = 0; r < 4; r++) inv[r] = 1.f / lacc[i][r];
#pragma unroll
    for (int r = 0; r < 4; r++) {
      int q = wv * 64 + i * 16 + lq * 4 + r;
      if (q < 196) {
        u16* op = ao + (size_t)(w * 196 + q) * 768 + h * 64 + lr;
#pragma unroll
        for (int j = 0; j < 4; j++)
          op[j * 16] = f2bf(oacc[i][j][r] * inv[r]);
      }
    }
  }
}

extern "C" void kernel_launch(void* const* d_in, const int* in_sizes, int n_in,
                              void* d_out, int out_size, void* d_ws, size_t ws_size,
                              hipStream_t stream) {
  const float* x      = (const float*)d_in[0];
  const float* qkv_w  = (const float*)d_in[1];
  const float* qkv_b  = (const float*)d_in[2];
  const float* proj_w = (const float*)d_in[3];
  const float* proj_b = (const float*)d_in[4];
  const float* rel_h  = (const float*)d_in[5];
  const float* rel_w  = (const float*)d_in[6];
  float* out = (float*)d_out;

  char* ws = (char*)d_ws;
  u16* Xw   = (u16*)ws;                                                   // MPAD*768 bf16, reused as attn_out
  u16* qkvb = (u16*)(ws + (size_t)MPAD * 768 * 2);                        // MPAD*2304 bf16 (rows >= MREAL unwritten)
  u16* qwb  = (u16*)(ws + (size_t)MPAD * 768 * 2 + (size_t)MPAD * 2304 * 2);
  u16* pwb  = (u16*)((char*)qwb + (size_t)2304 * 768 * 2);
  // cos/sin table hides in the unwritten tail of qkvb (rows 39232+; gemm1 skips m>=MREAL)
  float2* cs = (float2*)((char*)qkvb + (size_t)39232 * 2304 * 2);

  prep_w<<<6912, 256, 0, stream>>>(qkv_w, proj_w, qwb, pwb, cs);
  build_xw<<<MPAD * 3, 256, 0, stream>>>(x, Xw);
  gemm_bt<0><<<dim3(18, 307), 256, 0, stream>>>(Xw, qwb, qkv_b, qkvb, nullptr, 768, 2304);
  attn_mfma<<<2400, 256, LDS_TOT, stream>>>(qkvb, Xw, rel_h, rel_w, cs);
  gemm_bt<1><<<dim3(6, 307), 256, 0, stream>>>(Xw, pwb, proj_b, nullptr, out, 768, 768);
}

// Round 4
// 761.822 us; speedup vs baseline: 4.1553x; 1.0387x over previous
//
#include <hip/hip_runtime.h>

using u16 = unsigned short;
using u32 = unsigned int;

typedef __bf16 bf16x8 __attribute__((ext_vector_type(8)));
typedef float f32x4 __attribute__((ext_vector_type(4)));

#define MREAL 39200   // 200 windows * 196 tokens
#define MPAD  39296   // padded to 307*128

__device__ __forceinline__ u16 f2bf(float f) {
  u32 u = __float_as_uint(f);
  u += 0x7fffu + ((u >> 16) & 1u);   // RNE
  return (u16)(u >> 16);
}
__device__ __forceinline__ u32 pkbf(float a, float b) {
  return (u32)f2bf(a) | ((u32)f2bf(b) << 16);
}
__device__ __forceinline__ float bflo(u32 w) { return __uint_as_float(w << 16); }
__device__ __forceinline__ float bfhi(u32 w) { return __uint_as_float(w & 0xffff0000u); }

__device__ __forceinline__ void async16(const void* g, void* l) {
  __builtin_amdgcn_global_load_lds((const __attribute__((address_space(1))) void*)g,
                                   (__attribute__((address_space(3))) void*)l, 16, 0, 0);
}

union frag { uint4 u; bf16x8 b; };

// ---------------- prep: weights fp32 -> bf16, rope cos/sin table ----------------
__global__ __launch_bounds__(256) void prep_w(const float* __restrict__ qw,
                                              const float* __restrict__ pw,
                                              u16* __restrict__ qwb, u16* __restrict__ pwb,
                                              float2* __restrict__ cs) {
  int i = blockIdx.x * 256 + threadIdx.x;
  if (i < 2304 * 768) qwb[i] = f2bf(qw[i]);
  if (i < 768 * 768)  pwb[i] = f2bf(pw[i]);
  if (i < 196 * 32) {
    int t = i >> 5, f = i & 31;
    float fr = powf(10000.f, -(float)(f & 15) * (1.f / 16.f));
    float ang = (f < 16 ? (float)(t % 14) : (float)(t / 14)) * fr;
    cs[i] = make_float2(cosf(ang), sinf(ang));
  }
}

// ---------------- window partition: x(8,64,64,768) fp32 -> Xw(MPAD,768) bf16 ----------------
__global__ __launch_bounds__(256) void build_xw(const float* __restrict__ x, u16* __restrict__ Xw) {
  int bid = blockIdx.x;
  int m = bid / 3;
  int c = (bid % 3) * 256 + threadIdx.x;
  float val = 0.f;
  if (m < MREAL) {
    int w = m / 196, t = m % 196;
    int b = w / 25, r = w % 25;
    int gh = (r / 5) * 14 + t / 14;
    int gw = (r % 5) * 14 + t % 14;
    if (gh < 64 && gw < 64)
      val = x[(((size_t)b * 64 + gh) * 64 + gw) * 768 + c];
  }
  Xw[(size_t)m * 768 + c] = f2bf(val);
}

// ---------------- NT GEMM (m97-style) ----------------
template<int EPI>
__global__ __launch_bounds__(256) void gemm_bt(
    const u16* __restrict__ A, const u16* __restrict__ B,
    const float* __restrict__ bias, u16* __restrict__ Cb,
    float* __restrict__ Cf, int K, int N)
{
  __shared__ u16 As[128 * 32];
  __shared__ u16 Bs[128 * 32];
  const int tid = threadIdx.x;
  const int m0 = blockIdx.y * 128;
  const int n0 = blockIdx.x * 128;
  const int lane = tid & 63;
  const int wv = tid >> 6;
  const int wm = wv >> 1, wn = wv & 1;
  const int lr = lane & 15, lq = lane >> 4;

  f32x4 acc[4][4];
#pragma unroll
  for (int i = 0; i < 4; i++)
#pragma unroll
    for (int j = 0; j < 4; j++)
      acc[i][j] = f32x4{0.f, 0.f, 0.f, 0.f};

  const int rr_ = tid >> 2, cq = tid & 3;
  const u16* A0 = A + (size_t)(m0 + rr_) * K + cq * 8;
  const u16* A1 = A0 + (size_t)64 * K;
  const u16* B0 = B + (size_t)(n0 + rr_) * K + cq * 8;
  const u16* B1 = B0 + (size_t)64 * K;

  for (int k0 = 0; k0 < K; k0 += 32) {
    __syncthreads();
    async16(A0 + k0, (void*)(As + tid * 8));
    async16(A1 + k0, (void*)(As + 2048 + tid * 8));
    async16(B0 + k0, (void*)(Bs + tid * 8));
    async16(B1 + k0, (void*)(Bs + 2048 + tid * 8));
    __syncthreads();

    frag af[4], bg[4];
#pragma unroll
    for (int i = 0; i < 4; i++) {
      af[i].u = *(const uint4*)(As + (wm * 64 + i * 16 + lr) * 32 + lq * 8);
      bg[i].u = *(const uint4*)(Bs + (wn * 64 + i * 16 + lr) * 32 + lq * 8);
    }
#pragma unroll
    for (int i = 0; i < 4; i++)
#pragma unroll
      for (int j = 0; j < 4; j++)
        acc[i][j] = __builtin_amdgcn_mfma_f32_16x16x32_bf16(af[i].b, bg[j].b, acc[i][j], 0, 0, 0);
  }

#pragma unroll
  for (int i = 0; i < 4; i++) {
#pragma unroll
    for (int j = 0; j < 4; j++) {
      const int n = n0 + wn * 64 + j * 16 + lr;
      const int mb = m0 + wm * 64 + i * 16 + lq * 4;
      const float bv = bias[n];
#pragma unroll
      for (int rr = 0; rr < 4; rr++) {
        float val = acc[i][j][rr] + bv;
        int m = mb + rr;
        if (EPI == 0) {
          if (m < MREAL) Cb[(size_t)m * N + n] = f2bf(val);
        } else {
          if (m < MREAL) {
            int wdx = m / 196, tt = m % 196;
            int b = wdx / 25, rwd = wdx % 25;
            int gh = (rwd / 5) * 14 + tt / 14;
            int gw = (rwd % 5) * 14 + tt % 14;
            if (gh < 64 && gw < 64)
              Cf[(((size_t)b * 64 + gh) * 64 + gw) * 768 + n] = val;
          }
        }
      }
    }
  }
}

// ---------------- MFMA attention ----------------
// One block per (window, head). 4 waves x 64 query rows (196 real, pad 256).
// Keys padded to 224. Aug K-dim = 96: [q/8 | RH 14 | RW 14 | -30 flag | 0 0 0].
// P = exp(s) (no max-subtract; scores are O(1) by construction), l via MFMA vs ones.
#define R1P 104   // K_aug / A_aug row pitch (bf16 elems)
#define VTP 232   // V^T row pitch
#define PBP 40    // P buffer row pitch
#define LDS_R1   (256 * R1P * 2)                 // 53248
#define LDS_VT   (64 * VTP * 2)                  // 29696  (aliases Th/Tw 28672)
#define LDS_PB   (4 * 64 * PBP * 2)              // 20480  (aliases RT 17408)
#define LDS_TOT  (LDS_R1 + LDS_VT + LDS_PB)      // 103424

__global__ __launch_bounds__(256, 1) void attn_mfma(
    const u16* __restrict__ qkv, u16* __restrict__ ao,
    const float* __restrict__ relph, const float* __restrict__ relpw,
    const float2* __restrict__ cs)
{
  extern __shared__ char smem[];
  u16*   R1  = (u16*)smem;                       // [256][R1P]
  u16*   VTb = (u16*)(smem + LDS_R1);            // V^T [64][VTP]
  u16*   Th  = VTb;                              // phase-A alias: [256][28]
  u16*   Tw  = VTb + 256 * 28;
  char*  PBr = smem + LDS_R1 + LDS_VT;
  float* RTh = (float*)PBr;                      // phase-A alias: [32][68]
  float* RTw = RTh + 32 * 68;

  const int blk = blockIdx.x;
  const int w = blk / 12, h = blk % 12;
  const int tid = threadIdx.x;
  const int lane = tid & 63, wv = tid >> 6;
  const int lr = lane & 15, lq = lane >> 4;

  // ---- phase 0: rel tables -> RT (rows 27..31 zero) ----
  for (int i = tid; i < 32 * 64; i += 256) {
    int r = i >> 6, d = i & 63;
    float vh = 0.f, vw = 0.f;
    if (r < 27) { vh = relph[r * 64 + d]; vw = relpw[r * 64 + d]; }
    RTh[r * 68 + d] = vh;
    RTw[r * 68 + d] = vw;
  }

  // ---- phase A1: roped, scaled q -> R1 cols 0..63 ----
  {
    float qf[64];
    if (tid < 196) {
      const u16* qp = qkv + (size_t)(w * 196 + tid) * 2304 + h * 64;
      uint4 q4[8];
#pragma unroll
      for (int u = 0; u < 8; u++) q4[u] = *(const uint4*)(qp + u * 8);
#pragma unroll
      for (int u = 0; u < 8; u++) {
        qf[u*8+0] = bflo(q4[u].x); qf[u*8+1] = bfhi(q4[u].x);
        qf[u*8+2] = bflo(q4[u].y); qf[u*8+3] = bfhi(q4[u].y);
        qf[u*8+4] = bflo(q4[u].z); qf[u*8+5] = bfhi(q4[u].z);
        qf[u*8+6] = bflo(q4[u].w); qf[u*8+7] = bfhi(q4[u].w);
      }
      const float2* ct = cs + tid * 32;
#pragma unroll
      for (int f = 0; f < 32; f++) {
        float2 c2 = ct[f];
        float xr = qf[2*f], xi = qf[2*f+1];
        qf[2*f]   = (xr * c2.x - xi * c2.y) * 0.125f;
        qf[2*f+1] = (xr * c2.y + xi * c2.x) * 0.125f;
      }
    } else {
#pragma unroll
      for (int d = 0; d < 64; d++) qf[d] = 0.f;
    }
    u16* dst = R1 + tid * R1P;
#pragma unroll
    for (int u = 0; u < 8; u++)
      *(uint4*)(dst + u * 8) = make_uint4(pkbf(qf[u*8+0], qf[u*8+1]), pkbf(qf[u*8+2], qf[u*8+3]),
                                          pkbf(qf[u*8+4], qf[u*8+5]), pkbf(qf[u*8+6], qf[u*8+7]));
  }
  __syncthreads();

  // ---- phase A2: A-frags (q part) + T tables via MFMA ----
  frag af[4][3];
#pragma unroll
  for (int i = 0; i < 4; i++)
#pragma unroll
    for (int kc = 0; kc < 2; kc++)
      af[i][kc].u = *(const uint4*)(R1 + (wv * 64 + i * 16 + lr) * R1P + kc * 32 + lq * 8);

#pragma unroll
  for (int n = 0; n < 2; n++) {
    f32x4 tah[4], taw[4];
#pragma unroll
    for (int i = 0; i < 4; i++) { tah[i] = f32x4{0,0,0,0}; taw[i] = f32x4{0,0,0,0}; }
#pragma unroll
    for (int kc = 0; kc < 2; kc++) {
      const float* ph = &RTh[(n * 16 + lr) * 68 + kc * 32 + lq * 8];
      const float* pw2 = &RTw[(n * 16 + lr) * 68 + kc * 32 + lq * 8];
      float4 ha = *(const float4*)ph, hb = *(const float4*)(ph + 4);
      float4 wa = *(const float4*)pw2, wb2 = *(const float4*)(pw2 + 4);
      frag bh, bw;
      bh.u = make_uint4(pkbf(ha.x, ha.y), pkbf(ha.z, ha.w), pkbf(hb.x, hb.y), pkbf(hb.z, hb.w));
      bw.u = make_uint4(pkbf(wa.x, wa.y), pkbf(wa.z, wa.w), pkbf(wb2.x, wb2.y), pkbf(wb2.z, wb2.w));
#pragma unroll
      for (int i = 0; i < 4; i++) {
        tah[i] = __builtin_amdgcn_mfma_f32_16x16x32_bf16(af[i][kc].b, bh.b, tah[i], 0, 0, 0);
        taw[i] = __builtin_amdgcn_mfma_f32_16x16x32_bf16(af[i][kc].b, bw.b, taw[i], 0, 0, 0);
      }
    }
    int jcol = n * 16 + lr;
    if (jcol < 28) {
#pragma unroll
      for (int i = 0; i < 4; i++)
#pragma unroll
        for (int r = 0; r < 4; r++) {
          int q = wv * 64 + i * 16 + lq * 4 + r;
          Th[q * 28 + jcol] = f2bf(tah[i][r] * 8.f);   // undo q*0.125
          Tw[q * 28 + jcol] = f2bf(taw[i][r] * 8.f);
        }
    }
  }
  __syncthreads();

  // ---- phase A3: gather RH/RW -> R1 cols 64..95 ----
  {
    u32 wb[16];
#pragma unroll
    for (int z = 0; z < 16; z++) wb[z] = 0;
    if (tid < 196) {
      int ty = tid / 14, tx = tid - ty * 14;
      const u16* thr = Th + tid * 28 + ty + 13;
      const u16* twr = Tw + tid * 28 + tx + 13;
#pragma unroll
      for (int p = 0; p < 7; p++) wb[p]     = (u32)thr[-(2*p)] | ((u32)thr[-(2*p+1)] << 16);
#pragma unroll
      for (int p = 0; p < 7; p++) wb[7 + p] = (u32)twr[-(2*p)] | ((u32)twr[-(2*p+1)] << 16);
    }
    wb[14] = 0xC1F0u;   // col 92 = bf16(-30); col 93 = 0
    u16* dst = R1 + tid * R1P + 64;
#pragma unroll
    for (int u = 0; u < 4; u++)
      *(uint4*)(dst + u * 8) = make_uint4(wb[u*4], wb[u*4+1], wb[u*4+2], wb[u*4+3]);
  }
  __syncthreads();

  // ---- phase A4: A-frag bias chunk ----
#pragma unroll
  for (int i = 0; i < 4; i++)
    af[i][2].u = *(const uint4*)(R1 + (wv * 64 + i * 16 + lr) * R1P + 64 + lq * 8);
  __syncthreads();

  // ---- phase B: K_aug -> R1 rows 0..223, V^T -> VTb ----
  // NOTE: all register arrays const-indexed only (round-3 bug: kw[ch>>1] runtime
  // index demoted kw[] to scratch -> 130 MB of scratch traffic per dispatch).
  if (tid < 224) {
    const bool real = tid < 196;
    u32 kw[32];
#pragma unroll
    for (int z = 0; z < 32; z++) kw[z] = 0;
    if (real) {
      const u16* kp = qkv + (size_t)(w * 196 + tid) * 2304 + 768 + h * 64;
      float kf[64];
      uint4 k4[8];
#pragma unroll
      for (int u = 0; u < 8; u++) k4[u] = *(const uint4*)(kp + u * 8);
#pragma unroll
      for (int u = 0; u < 8; u++) {
        kf[u*8+0] = bflo(k4[u].x); kf[u*8+1] = bfhi(k4[u].x);
        kf[u*8+2] = bflo(k4[u].y); kf[u*8+3] = bfhi(k4[u].y);
        kf[u*8+4] = bflo(k4[u].z); kf[u*8+5] = bfhi(k4[u].z);
        kf[u*8+6] = bflo(k4[u].w); kf[u*8+7] = bfhi(k4[u].w);
      }
      const float2* ct = cs + tid * 32;
#pragma unroll
      for (int f = 0; f < 32; f++) {
        float2 c2 = ct[f];
        float xr = kf[2*f], xi = kf[2*f+1];
        kf[2*f]   = xr * c2.x - xi * c2.y;
        kf[2*f+1] = xr * c2.y + xi * c2.x;
      }
#pragma unroll
      for (int p = 0; p < 32; p++) kw[p] = pkbf(kf[2*p], kf[2*p+1]);
    }
    // aug cols 64..95 branchless: one-hot of ky at 64..77, kx at 78..91;
    // pad keys instead get col 92 = 1.0 (dots with A col 92 = -30).
    const int ky = tid / 14, kx = tid - (tid / 14) * 14;
    const int tA = real ? 64 + ky : 92;
    const int tB = real ? 78 + kx : 92;
    u32 aw[16];
#pragma unroll
    for (int p = 0; p < 16; p++) {
      const int c0 = 64 + 2 * p, c1 = c0 + 1;
      u32 lo = (c0 == tA || c0 == tB) ? 0x3F80u : 0u;
      u32 hi = (c1 == tA || c1 == tB) ? 0x3F80u : 0u;
      aw[p] = lo | (hi << 16);
    }
    u16* dst = R1 + tid * R1P;
#pragma unroll
    for (int u = 0; u < 8; u++)
      *(uint4*)(dst + u * 8) = make_uint4(kw[u*4], kw[u*4+1], kw[u*4+2], kw[u*4+3]);
#pragma unroll
    for (int u = 0; u < 4; u++)
      *(uint4*)(dst + 64 + u * 8) = make_uint4(aw[u*4], aw[u*4+1], aw[u*4+2], aw[u*4+3]);

    // V^T (keep raw bf16 bits)
    if (real) {
      const u16* vp = qkv + (size_t)(w * 196 + tid) * 2304 + 1536 + h * 64;
#pragma unroll
      for (int u = 0; u < 8; u++) {
        uint4 v4 = *(const uint4*)(vp + u * 8);
        u16* col = VTb + tid;
        col[(u*8+0) * VTP] = (u16)(v4.x & 0xffff); col[(u*8+1) * VTP] = (u16)(v4.x >> 16);
        col[(u*8+2) * VTP] = (u16)(v4.y & 0xffff); col[(u*8+3) * VTP] = (u16)(v4.y >> 16);
        col[(u*8+4) * VTP] = (u16)(v4.z & 0xffff); col[(u*8+5) * VTP] = (u16)(v4.z >> 16);
        col[(u*8+6) * VTP] = (u16)(v4.w & 0xffff); col[(u*8+7) * VTP] = (u16)(v4.w >> 16);
      }
    } else {
#pragma unroll
      for (int d = 0; d < 64; d++) VTb[d * VTP + tid] = 0;
    }
  }
  __syncthreads();

  // ---- main loop: 7 chunks of 32 keys, barrier-free ----
  f32x4 oacc[4][4];
  f32x4 lacc[4];
#pragma unroll
  for (int i = 0; i < 4; i++) {
    lacc[i] = f32x4{0,0,0,0};
#pragma unroll
    for (int j = 0; j < 4; j++) oacc[i][j] = f32x4{0,0,0,0};
  }
  frag ones;
  ones.u = make_uint4(0x3F803F80u, 0x3F803F80u, 0x3F803F80u, 0x3F803F80u);
  u16* PB = (u16*)PBr + wv * 64 * PBP;

  for (int c = 0; c < 7; c++) {
    frag bk[2][3];
#pragma unroll
    for (int kt = 0; kt < 2; kt++)
#pragma unroll
      for (int kc = 0; kc < 3; kc++)
        bk[kt][kc].u = *(const uint4*)(R1 + (c * 32 + kt * 16 + lr) * R1P + kc * 32 + lq * 8);

    f32x4 sacc[4][2];
#pragma unroll
    for (int i = 0; i < 4; i++) { sacc[i][0] = f32x4{0,0,0,0}; sacc[i][1] = f32x4{0,0,0,0}; }
#pragma unroll
    for (int kc = 0; kc < 3; kc++)
#pragma unroll
      for (int i = 0; i < 4; i++)
#pragma unroll
        for (int kt = 0; kt < 2; kt++)
          sacc[i][kt] = __builtin_amdgcn_mfma_f32_16x16x32_bf16(af[i][kc].b, bk[kt][kc].b, sacc[i][kt], 0, 0, 0);

    // P = exp(s) -> wave-private LDS (C-layout store, A-layout read)
#pragma unroll
    for (int i = 0; i < 4; i++)
#pragma unroll
      for (int kt = 0; kt < 2; kt++)
#pragma unroll
        for (int r = 0; r < 4; r++)
          PB[(i * 16 + lq * 4 + r) * PBP + kt * 16 + lr] = f2bf(__expf(sacc[i][kt][r]));

    frag pf[4];
#pragma unroll
    for (int i = 0; i < 4; i++)
      pf[i].u = *(const uint4*)(PB + (i * 16 + lr) * PBP + lq * 8);

#pragma unroll
    for (int i = 0; i < 4; i++)
      lacc[i] = __builtin_amdgcn_mfma_f32_16x16x32_bf16(pf[i].b, ones.b, lacc[i], 0, 0, 0);

    frag bv[4];
#pragma unroll
    for (int j = 0; j < 4; j++)
      bv[j].u = *(const uint4*)(VTb + (j * 16 + lr) * VTP + c * 32 + lq * 8);
#pragma unroll
    for (int i = 0; i < 4; i++)
#pragma unroll
      for (int j = 0; j < 4; j++)
        oacc[i][j] = __builtin_amdgcn_mfma_f32_16x16x32_bf16(pf[i].b, bv[j].b, oacc[i][j], 0, 0, 0);
  }

  // ---- epilogue: O / l -> ao [m][C] bf16 ----
#pragma unroll
  for (int i = 0; i < 4; i++) {
    f32x4 inv;
#pragma unroll
    for (int r = 0; r < 4; r++) inv[r] = 1.f / lacc[i][r];
#pragma unroll
    for (int r = 0; r < 4; r++) {
      int q = wv * 64 + i * 16 + lq * 4 + r;
      if (q < 196) {
        u16* op = ao + (size_t)(w * 196 + q) * 768 + h * 64 + lr;
#pragma unroll
        for (int j = 0; j < 4; j++)
          op[j * 16] = f2bf(oacc[i][j][r] * inv[r]);
      }
    }
  }
}

extern "C" void kernel_launch(void* const* d_in, const int* in_sizes, int n_in,
                              void* d_out, int out_size, void* d_ws, size_t ws_size,
                              hipStream_t stream) {
  const float* x      = (const float*)d_in[0];
  const float* qkv_w  = (const float*)d_in[1];
  const float* qkv_b  = (const float*)d_in[2];
  const float* proj_w = (const float*)d_in[3];
  const float* proj_b = (const float*)d_in[4];
  const float* rel_h  = (const float*)d_in[5];
  const float* rel_w  = (const float*)d_in[6];
  float* out = (float*)d_out;

  char* ws = (char*)d_ws;
  u16* Xw   = (u16*)ws;                                                   // MPAD*768 bf16, reused as attn_out
  u16* qkvb = (u16*)(ws + (size_t)MPAD * 768 * 2);                        // MPAD*2304 bf16 (rows >= MREAL unwritten)
  u16* qwb  = (u16*)(ws + (size_t)MPAD * 768 * 2 + (size_t)MPAD * 2304 * 2);
  u16* pwb  = (u16*)((char*)qwb + (size_t)2304 * 768 * 2);
  // cos/sin table hides in the unwritten tail of qkvb (rows 39232+; gemm1 skips m>=MREAL)
  float2* cs = (float2*)((char*)qkvb + (size_t)39232 * 2304 * 2);

  prep_w<<<6912, 256, 0, stream>>>(qkv_w, proj_w, qwb, pwb, cs);
  build_xw<<<MPAD * 3, 256, 0, stream>>>(x, Xw);
  gemm_bt<0><<<dim3(18, 307), 256, 0, stream>>>(Xw, qwb, qkv_b, qkvb, nullptr, 768, 2304);
  attn_mfma<<<2400, 256, LDS_TOT, stream>>>(qkvb, Xw, rel_h, rel_w, cs);
  gemm_bt<1><<<dim3(6, 307), 256, 0, stream>>>(Xw, pwb, proj_b, nullptr, out, 768, 768);
}